// Round 8
// baseline (390.202 us; speedup 1.0000x reference)
//
#include <hip/hip_runtime.h>
#include <hip/hip_bf16.h>

// GRU teacher-forced NLL, B=8192, S=2048, H=8, IN_DIM=4, NCLS=10.
// 8 lanes/element, 1 wave/SIMD (structural: 8192*8 lanes = 1024 waves).
// R7 math kept exactly; step body rewritten as straight-line code interleaved
// for IN-ORDER issue: trans ops issued as early as possible, with independent
// work (logit dots, lag-2 softmax consume, pending bookkeeping) placed inside
// each trans shadow. Trans budget is minimal at 7/step (er, ez, E, 2 rcp,
// 2 consume exp2); the win target is schedule length, not issue count.

#define SEQ   2048
#define BATCH 8192

using hh2 = decltype(__builtin_amdgcn_cvt_pkrtz(0.0f, 0.0f));

template <int CTRL>
static __device__ __forceinline__ int dppi(int x) {
    return __builtin_amdgcn_update_dpp(x, x, CTRL, 0xF, 0xF, true);
}
static __device__ __forceinline__ float xor1f(float x) {
    return __builtin_bit_cast(float, dppi<0xB1>(__builtin_bit_cast(int, x)));
}
static __device__ __forceinline__ float xor2f(float x) {
    return __builtin_bit_cast(float, dppi<0x4E>(__builtin_bit_cast(int, x)));
}
static __device__ __forceinline__ float hmf(float x) {   // lane ^ 7 (ROW_HALF_MIRROR)
    return __builtin_bit_cast(float, dppi<0x141>(__builtin_bit_cast(int, x)));
}
static __device__ __forceinline__ hh2 xor2h(hh2 x) {
    return __builtin_bit_cast(hh2, dppi<0x4E>(__builtin_bit_cast(int, x)));
}
static __device__ __forceinline__ hh2 hmfh(hh2 x) {
    return __builtin_bit_cast(hh2, dppi<0x141>(__builtin_bit_cast(int, x)));
}
static __device__ __forceinline__ float dot2(hh2 a, hh2 b, float c) {
    return __builtin_amdgcn_fdot2(a, b, c, false);
}

__global__ __launch_bounds__(256, 1)
void gru_nll_kernel(const int* __restrict__ xb,
                    const float* __restrict__ Wir, const float* __restrict__ bir,
                    const float* __restrict__ Wiz, const float* __restrict__ biz,
                    const float* __restrict__ Win, const float* __restrict__ bin_,
                    const float* __restrict__ Whr, const float* __restrict__ bhr,
                    const float* __restrict__ Whz, const float* __restrict__ bhz,
                    const float* __restrict__ Whn, const float* __restrict__ bhn,
                    const float* __restrict__ Wout, const float* __restrict__ bout,
                    float* __restrict__ out)
{
    constexpr float S1 = 1.4426950408889634f;   // log2(e)
    __shared__ float4 tbl[10][8];               // [count][i] = {gr', gz', gn', 0}
    __shared__ float  red[256];

    const int tid = threadIdx.x;

    if (tid < 80) {
        int c = tid >> 3, ii = tid & 7;
        float b0 = (float)((c >> 3) & 1);
        float b1 = (float)((c >> 2) & 1);
        float b2 = (float)((c >> 1) & 1);
        float b3 = (float)(c & 1);
        float gr = bir[ii] + bhr[ii]
                 + b0*Wir[ii*4+0] + b1*Wir[ii*4+1] + b2*Wir[ii*4+2] + b3*Wir[ii*4+3];
        float gz = biz[ii] + bhz[ii]
                 + b0*Wiz[ii*4+0] + b1*Wiz[ii*4+1] + b2*Wiz[ii*4+2] + b3*Wiz[ii*4+3];
        float gn = bin_[ii]
                 + b0*Win[ii*4+0] + b1*Win[ii*4+1] + b2*Win[ii*4+2] + b3*Win[ii*4+3];
        tbl[c][ii] = make_float4(S1 * gr, S1 * gz, 2.0f * S1 * gn, 0.0f);
    }
    __syncthreads();

    const int lane = tid & 63;
    const int i    = lane & 7;                    // hidden comp / class owned
    const int b    = blockIdx.x * 32 + (tid >> 3);

    const int perm[8] = {0, 1, 2, 3, 7, 6, 5, 4};

    hh2 whr[4], whz[4], whn[4], wA[4], wB[4];
    #pragma unroll
    for (int q = 0; q < 4; ++q) {
        int c0 = i ^ perm[2*q], c1 = i ^ perm[2*q+1];
        whr[q] = __builtin_amdgcn_cvt_pkrtz(S1 * Whr[i*8 + c0],      S1 * Whr[i*8 + c1]);
        whz[q] = __builtin_amdgcn_cvt_pkrtz(S1 * Whz[i*8 + c0],      S1 * Whz[i*8 + c1]);
        whn[q] = __builtin_amdgcn_cvt_pkrtz(2.0f*S1 * Whn[i*8 + c0], 2.0f*S1 * Whn[i*8 + c1]);
        wA[q]  = __builtin_amdgcn_cvt_pkrtz(S1 * Wout[i*8 + c0],     S1 * Wout[i*8 + c1]);
        wB[q]  = (i < 2)
               ? __builtin_amdgcn_cvt_pkrtz(S1 * Wout[(8+i)*8 + c0], S1 * Wout[(8+i)*8 + c1])
               : __builtin_amdgcn_cvt_pkrtz(0.0f, 0.0f);
    }
    const float ghn_b = 2.0f * S1 * bhn[i];
    const float bA    = S1 * bout[i];
    const float bB    = (i < 2) ? S1 * bout[8+i] : -1e30f;   // exp2 -> 0
    const int clsA    = i;
    const int clsB    = (i < 2) ? 8 + i : 99;                // 99: never matches

    const int4* row4 = (const int4*)(xb + (size_t)b * SEQ);

    hh2 Hh[4];
    #pragma unroll
    for (int q = 0; q < 4; ++q) Hh[q] = __builtin_amdgcn_cvt_pkrtz(0.0f, 0.0f);
    float hprev = 0.0f;                     // own h_i, exact fp32

    float acct = 0.0f;                      // target logits (base-2), x1/elem
    float P    = 1.0f;

    // pending: pLA/pLB = logits of step cur-2 (consumed during step cur);
    // tq2 = its target; tq1 = target of step cur-1
    float pLA = 0.0f, pLB = -1e30f;         // dummy: s-sum = 8 exactly
    int   tq1 = -1, tq2 = -1;

    // pre-subtract dummy contributions EXACTLY (same-op recompute)
    float accp;
    {
        float s0 = __builtin_amdgcn_exp2f(bA) + __builtin_amdgcn_exp2f(bB);
        s0 += xor1f(s0);
        s0 += xor2f(s0);
        s0 += hmf(s0);
        accp = -3.0f - __builtin_amdgcn_logf(s0);
    }

    float4 g = tbl[0][i];                   // first input count = 0

    auto stepf = [&](int t) {
        // next step's table entry (ds latency covered by the whole step)
        float4 gnx = *(const float4*)&tbl[t][i];

        // ---- gate dots on H = h_{cur-1} ----
        float ar = g.x, az = g.y, hn = ghn_b;
        #pragma unroll
        for (int q = 0; q < 4; ++q) {
            ar = dot2(Hh[q], whr[q], ar);
            az = dot2(Hh[q], whz[q], az);
            hn = dot2(Hh[q], whn[q], hn);
        }

        // ---- trans front: issue both sigmoid exps ASAP ----
        float er = __builtin_amdgcn_exp2f(-ar);
        float ez = __builtin_amdgcn_exp2f(-az);

        // ---- filler 1: lagged logits of step cur-1 (same H regs) ----
        float lA = bA, lB = bB;
        #pragma unroll
        for (int q = 0; q < 4; ++q) {
            lA = dot2(Hh[q], wA[q], lA);
            lB = dot2(Hh[q], wB[q], lB);
        }

        // ---- filler 2: lag-2 consume exps (independent) ----
        float sA = __builtin_amdgcn_exp2f(pLA);
        float sB = __builtin_amdgcn_exp2f(pLB);

        // r = 1/(1+er)  (er ready by now)
        float ir = __builtin_amdgcn_rcpf(1.0f + er);

        // ---- filler 3: softmax reduce + product + target select ----
        float s = sA + sB;
        s += xor1f(s);
        s += xor2f(s);
        s += hmf(s);            // quad sums quad-uniform: xor7 == xor4
        P *= s;
        float sel = (tq2 == clsA) ? pLA : ((tq2 == clsB) ? pLB : 0.0f);
        acct += sel;

        // ---- u, E ----
        float u = __builtin_fmaf(hn, ir, g.z);
        float E = __builtin_amdgcn_exp2f(u);

        // ---- filler 4: pending bookkeeping inside E's shadow ----
        pLA = lA; pLB = lB;
        tq2 = tq1; tq1 = t;
        float ezp1 = 1.0f + ez;

        // ---- merged z/tanh update: hnew = [h0(E+1)+ez(E-1)]/[(1+ez)(E+1)] ----
        float a_  = E + 1.0f;
        float c_  = E - 1.0f;
        float m_  = ez * c_;
        float num = __builtin_fmaf(hprev, a_, m_);
        float den = a_ * ezp1;
        float rd  = __builtin_amdgcn_rcpf(den);
        float hnew = num * rd;
        hprev = hnew;

        // ---- packed-f16 butterfly ----
        float v1 = xor1f(hnew);
        hh2 p0 = __builtin_amdgcn_cvt_pkrtz(hnew, v1);
        Hh[0] = p0;
        Hh[1] = xor2h(p0);      // (h_{i^2}, h_{i^3})
        Hh[2] = hmfh(p0);       // (h_{i^7}, h_{i^6})
        Hh[3] = hmfh(Hh[1]);    // (h_{i^5}, h_{i^4})

        g = gnx;
    };

    int4 cc = row4[0];
    int4 cd = row4[1];
    for (int jb = 0; jb < SEQ/8; ++jb) {
        int nidx = (jb + 1 < SEQ/8) ? (2*jb + 2) : 0;
        int4 nA = row4[nidx];
        int4 nB = row4[nidx + 1];
        stepf(cc.x); stepf(cc.y); stepf(cc.z); stepf(cc.w);
        stepf(cd.x); stepf(cd.y); stepf(cd.z); stepf(cd.w);
        accp += __builtin_amdgcn_logf(P);   // log2
        P = 1.0f;
        cc = nA; cd = nB;
    }

    // tail: consume step SEQ-2, then logits+consume for step SEQ-1
    {
        float s = __builtin_amdgcn_exp2f(pLA) + __builtin_amdgcn_exp2f(pLB);
        s += xor1f(s);
        s += xor2f(s);
        s += hmf(s);
        P *= s;
        float sel = (tq2 == clsA) ? pLA : ((tq2 == clsB) ? pLB : 0.0f);
        acct += sel;
    }
    {
        float lA = bA, lB = bB;
        #pragma unroll
        for (int q = 0; q < 4; ++q) {
            lA = dot2(Hh[q], wA[q], lA);
            lB = dot2(Hh[q], wB[q], lB);
        }
        float s = __builtin_amdgcn_exp2f(lA) + __builtin_amdgcn_exp2f(lB);
        s += xor1f(s);
        s += xor2f(s);
        s += hmf(s);
        P *= s;
        float sel = (tq1 == clsA) ? lA : ((tq1 == clsB) ? lB : 0.0f);
        acct += sel;
    }
    accp += __builtin_amdgcn_logf(P);

    red[tid] = __builtin_fmaf(accp, 0.125f, -acct);
    __syncthreads();
    #pragma unroll
    for (int sft = 128; sft > 0; sft >>= 1) {
        if (tid < sft) red[tid] += red[tid + sft];
        __syncthreads();
    }
    if (tid == 0) {
        constexpr float SCALE =
            (float)(0.69314718055994530942 / (8192.0 * 2048.0));
        atomicAdd(out, red[0] * SCALE);
    }
}

extern "C" void kernel_launch(void* const* d_in, const int* in_sizes, int n_in,
                              void* d_out, int out_size, void* d_ws, size_t ws_size,
                              hipStream_t stream) {
    (void)hipMemsetAsync(d_out, 0, sizeof(float), stream);
    gru_nll_kernel<<<BATCH * 8 / 256, 256, 0, stream>>>(
        (const int*)d_in[0],
        (const float*)d_in[1],  (const float*)d_in[2],
        (const float*)d_in[3],  (const float*)d_in[4],
        (const float*)d_in[5],  (const float*)d_in[6],
        (const float*)d_in[7],  (const float*)d_in[8],
        (const float*)d_in[9],  (const float*)d_in[10],
        (const float*)d_in[11], (const float*)d_in[12],
        (const float*)d_in[13], (const float*)d_in[14],
        (float*)d_out);
}